// Round 2
// baseline (358.741 us; speedup 1.0000x reference)
//
#include <hip/hip_runtime.h>
#include <math.h>

// Problem constants (match reference)
#define NN 50000   // nodes
#define EE 800000  // edges
#define FF 128     // node features
#define CC 11      // spline coeffs per feature (G+K)
#define O2 256     // combined outputs: 128 src-proj + 128 dst-proj
#define KT 1536    // true K: 128 features x 12 slots (11 spline + silu)
#define NPB 782    // proj blocks: ceil(NN/64)
#define NCB 782    // count blocks: ceil(EE/(256*4))

typedef __attribute__((ext_vector_type(8))) short short8;
typedef __attribute__((ext_vector_type(4))) float f32x4;
typedef unsigned int uint;
typedef unsigned short ushort;

__device__ __forceinline__ ushort bf16_rne(float v) {
  uint u = __float_as_uint(v);
  u = u + 0x7FFFu + ((u >> 16) & 1u);
  return (ushort)(u >> 16);
}
__device__ __forceinline__ float bf_lo(uint u) { return __uint_as_float(u << 16); }
__device__ __forceinline__ float bf_hi(uint u) { return __uint_as_float(u & 0xffff0000u); }

// Repack weights to MFMA-fragment-contiguous bf16 layout:
// Wh[((g*16 + cg)*64 + lane)*8 + j] = W^T[col = cg*16+(lane&15)][k = g*32+(lane>>4)*8+j]
// so a wave's B-fragment load for (window g, col-group cg) is one coalesced 1KB read.
// Also zero deg (fused, removes memset dispatch).
__global__ __launch_bounds__(256) void repack_zero_kernel(
    const float* __restrict__ bws, const float* __restrict__ sws,
    const float* __restrict__ bwd, const float* __restrict__ swd,
    ushort* __restrict__ Wh, int* __restrict__ deg) {
  int idx = blockIdx.x * 256 + threadIdx.x;
  if (idx < NN) deg[idx] = 0;
  if (idx >= O2 * KT) return;
  int j = idx & 7;
  int lane = (idx >> 3) & 63;
  int cg = (idx >> 9) & 15;
  int g = idx >> 13;  // 0..47
  int col = cg * 16 + (lane & 15);
  int k = g * 32 + (lane >> 4) * 8 + j;
  int f = k / 12;
  int ch = k - f * 12;
  const float* bw = (col < 128) ? bws : bwd;
  const float* sw = (col < 128) ? sws : swd;
  int o = col & 127;
  float v = (ch == 11) ? bw[(size_t)o * FF + f] : sw[((size_t)o * FF + f) * CC + ch];
  Wh[idx] = bf16_rne(v);
}

// Fused dispatch: blocks [0,NPB) = MFMA projection; blocks [NPB,NPB+NCB) =
// degree count (4 edges/thread, int4).
//
// Projection, BARRIER-FREE: 4 waves/block, each wave owns a 32-node x 128-col
// tile (acc[2][8] = 64 VGPR) and stages its OWN nodes' spline rows into its
// OWN LDS slice (wave-synchronous: only lgkmcnt ordering, zero s_barrier).
// K iterated as 16 trios (8 features = 96 slots = 3 MFMA windows), A-tile
// double-buffered, x prefetched one trio ahead (float4/lane). B loaded from
// the fragment-contiguous Wh (8 coalesced 1KB loads per window -> deep ILP).
__global__ __launch_bounds__(256, 3) void proj_count_kernel(
    const float* __restrict__ x, const ushort* __restrict__ Wh,
    uint* __restrict__ projB, const int* __restrict__ ei, int* __restrict__ deg) {
  __shared__ ushort Ah[4][2][32][104];  // [wave][dbuf][node][96 slots + 8 pad] = 53,248 B
  if (blockIdx.x >= NPB) {  // ---- count part ----
    int base = ((blockIdx.x - NPB) * 256 + threadIdx.x) * 4;
    if (base + 3 < EE) {
      int4 dd = *(const int4*)(ei + EE + base);
      atomicAdd(&deg[dd.x], 1);
      atomicAdd(&deg[dd.y], 1);
      atomicAdd(&deg[dd.z], 1);
      atomicAdd(&deg[dd.w], 1);
    } else {
      for (int j = 0; j < 4 && base + j < EE; ++j) atomicAdd(&deg[ei[EE + base + j]], 1);
    }
    return;
  }
  const int t = threadIdx.x;
  const int lane = t & 63;
  const int w = t >> 6;        // wave 0..3
  const int m = lane & 15;
  const int q = lane >> 4;     // quad
  const int ns = w >> 1;       // node subgroup (0/1): nodes ns*32..ns*32+31
  const int h = w & 1;         // col half: cols h*128..h*128+127
  const int block0 = blockIdx.x * 64;

  // staging role: lane -> (node sn, feature quartet sf)
  const int sn = lane & 31;
  const int sf = lane >> 5;
  const int node_s = block0 + ns * 32 + sn;
  const bool valid_s = (node_s < NN);

  // Stage 4 features (sf*4+i of trio) for node sn into buf. Wave-private.
  auto stage = [&](int buf, float4 xq) {
    ushort* base = &Ah[w][buf][sn][sf * 48];
    uint4* z = (uint4*)base;
#pragma unroll
    for (int i = 0; i < 6; ++i) z[i] = make_uint4(0u, 0u, 0u, 0u);
    float xa[4] = {xq.x, xq.y, xq.z, xq.w};
#pragma unroll
    for (int i = 0; i < 4; ++i) {
      float xv = xa[i];
      ushort* row = base + i * 12;
      row[11] = bf16_rne(xv / (1.f + __expf(-xv)));  // silu slot
      float u = fmaf(xv, 4.f, 7.f);
      float fj = floorf(u);
      int jj = (int)fj;
      if (jj >= 0 && jj <= 13) {
        float tt = u - fj;
        float t2 = tt * tt, t3 = t2 * tt;
        float w0 = (1.f / 6.f) * (1.f - 3.f * tt + 3.f * t2 - t3);
        float w1 = (1.f / 6.f) * (4.f - 6.f * t2 + 3.f * t3);
        float w2 = (1.f / 6.f) * (1.f + 3.f * tt + 3.f * t2 - 3.f * t3);
        float w3 = (1.f / 6.f) * t3;
        float wv[4] = {w0, w1, w2, w3};
        int i0 = jj - 3;
#pragma unroll
        for (int c2 = 0; c2 < 4; ++c2) {
          int sidx = i0 + c2;
          if (sidx >= 0 && sidx <= 10) row[sidx] = bf16_rne(wv[c2]);
        }
      }
    }
  };

  const float4 zero4 = make_float4(0.f, 0.f, 0.f, 0.f);
  auto loadx = [&](int G) -> float4 {
    if (!valid_s) return zero4;
    return *(const float4*)(x + (size_t)node_s * FF + 8 * G + 4 * sf);
  };

  f32x4 acc[2][8];
#pragma unroll
  for (int r = 0; r < 2; ++r)
#pragma unroll
    for (int c = 0; c < 8; ++c) acc[r][c] = (f32x4)(0.f);

  float4 xc = loadx(0);
  stage(0, xc);
  float4 xn = loadx(1);

  for (int G = 0; G < 16; ++G) {
    if (G + 1 < 16) {
      stage((G + 1) & 1, xn);
      if (G + 2 < 16) xn = loadx(G + 2);
    }
#pragma unroll
    for (int wi = 0; wi < 3; ++wi) {
      int g = 3 * G + wi;
      const ushort* bp = Wh + (size_t)g * 8192 + (size_t)h * 4096 + (size_t)lane * 8;
      short8 a0 = *(const short8*)(&Ah[w][G & 1][m][wi * 32 + q * 8]);
      short8 a1 = *(const short8*)(&Ah[w][G & 1][16 + m][wi * 32 + q * 8]);
#pragma unroll
      for (int c = 0; c < 8; ++c) {
        short8 b = *(const short8*)(bp + (size_t)c * 512);
        acc[0][c] = __builtin_amdgcn_mfma_f32_16x16x32_bf16(a0, b, acc[0][c], 0, 0, 0);
        acc[1][c] = __builtin_amdgcn_mfma_f32_16x16x32_bf16(a1, b, acc[1][c], 0, 0, 0);
      }
    }
  }
  // epilogue: C/D layout col=lane&15, row=quad*4+reg (verified m89/m91).
  // wave cols = h*128 + c*16 + m; pair (c=2u, 2u+1) -> projB group q' = h*4+u.
#pragma unroll
  for (int r = 0; r < 2; ++r) {
#pragma unroll
    for (int reg = 0; reg < 4; ++reg) {
      int nd = block0 + ns * 32 + r * 16 + q * 4 + reg;
      if (nd < NN) {
#pragma unroll
        for (int u = 0; u < 4; ++u) {
          uint val = (uint)bf16_rne(acc[r][2 * u][reg]) |
                     ((uint)bf16_rne(acc[r][2 * u + 1][reg]) << 16);
          projB[(size_t)nd * 128 + (h * 4 + u) * 16 + m] = val;
        }
      }
    }
  }
}

// ---- CSR build ----
__global__ __launch_bounds__(256) void scanA_kernel(
    const int* __restrict__ deg, int* __restrict__ ex, int* __restrict__ partial) {
  __shared__ int sd[256];
  int t = threadIdx.x;
  int idx = blockIdx.x * 256 + t;
  int v = (idx < NN) ? deg[idx] : 0;
  sd[t] = v;
  __syncthreads();
#pragma unroll
  for (int off = 1; off < 256; off <<= 1) {
    int add = (t >= off) ? sd[t - off] : 0;
    __syncthreads();
    sd[t] += add;
    __syncthreads();
  }
  if (idx < NN) ex[idx] = sd[t] - v;
  if (t == 255) partial[blockIdx.x] = sd[255];
}

__global__ __launch_bounds__(256) void scanB_kernel(
    const int* __restrict__ partial, int* __restrict__ poff, int nblk) {
  __shared__ int sd[256];
  int t = threadIdx.x;
  int v = (t < nblk) ? partial[t] : 0;
  sd[t] = v;
  __syncthreads();
#pragma unroll
  for (int off = 1; off < 256; off <<= 1) {
    int add = (t >= off) ? sd[t - off] : 0;
    __syncthreads();
    sd[t] += add;
    __syncthreads();
  }
  if (t < nblk) poff[t] = sd[t] - v;
}

__global__ __launch_bounds__(256) void scanC_kernel(
    const int* __restrict__ ex, const int* __restrict__ poff,
    int* __restrict__ row_ptr, int* __restrict__ cur) {
  int idx = blockIdx.x * 256 + threadIdx.x;
  if (idx < NN) {
    int v = ex[idx] + poff[idx >> 8];
    row_ptr[idx] = v;
    cur[idx] = v;
  }
  if (idx == 0) row_ptr[NN] = EE;
}

// 2 edges/thread, int2 loads; store SRC id directly
__global__ __launch_bounds__(256) void fill_kernel(
    const int* __restrict__ ei, int* __restrict__ cur, int* __restrict__ scsr) {
  int base = (blockIdx.x * 256 + threadIdx.x) * 2;
  if (base + 1 < EE) {
    int2 ss = *(const int2*)(ei + base);
    int2 dd = *(const int2*)(ei + EE + base);
    int p0 = atomicAdd(&cur[dd.x], 1);
    scsr[p0] = ss.x;
    int p1 = atomicAdd(&cur[dd.y], 1);
    scsr[p1] = ss.y;
  } else if (base < EE) {
    int s = ei[base], d = ei[EE + base];
    scsr[atomicAdd(&cur[d], 1)] = s;
  }
}

// Per-dst aggregation: one wave per dst, 4 edges in flight (16-lane groups),
// 2-deep gather pipeline (src idx 3 ahead, row data 2 ahead).
__global__ __launch_bounds__(256) void aggr_kernel(
    const uint* __restrict__ projB, const int* __restrict__ scsr,
    const int* __restrict__ row_ptr, const float* __restrict__ av,
    const float* __restrict__ x, const float* __restrict__ bias,
    const float* __restrict__ pa, float* __restrict__ out) {
  int d = blockIdx.x * 4 + (threadIdx.x >> 6);
  if (d >= NN) return;
  int l = threadIdx.x & 63;
  int g = l >> 4, m = l & 15;
  const uint4* pb4 = (const uint4*)projB;
  uint4 dpu = pb4[(size_t)d * 32 + 16 + m];
  uint du[4] = {dpu.x, dpu.y, dpu.z, dpu.w};
  float dplo[4], dphi[4], avlo[4], avhi[4];
  int cl[4];
#pragma unroll
  for (int j = 0; j < 4; ++j) {
    dplo[j] = bf_lo(du[j]);
    dphi[j] = bf_hi(du[j]);
    int p = 4 * m + j;
    cl[j] = ((p >> 4) << 5) + (p & 15);
    avlo[j] = av[cl[j]];
    avhi[j] = av[cl[j] + 16];
  }
  int i0 = row_ptr[d], i1 = row_ptr[d + 1];
  float acl[4] = {0.f, 0.f, 0.f, 0.f}, ach[4] = {0.f, 0.f, 0.f, 0.f};
  float den = 0.f;
  int i = i0 + g;
  if (i < i1) {
    int s0 = scsr[i];
    int s1 = (i + 4 < i1) ? scsr[i + 4] : s0;
    int s2 = (i + 8 < i1) ? scsr[i + 8] : s1;
    uint4 U0 = pb4[(size_t)s0 * 32 + m];
    uint4 U1 = pb4[(size_t)s1 * 32 + m];
    for (; i < i1; i += 4) {
      int s3 = (i + 12 < i1) ? scsr[i + 12] : s2;
      uint4 U2 = pb4[(size_t)s2 * 32 + m];  // 2-ahead, issues immediately
      uint uu[4] = {U0.x, U0.y, U0.z, U0.w};
      float slo[4], shi[4];
      float vp = 0.f;
#pragma unroll
      for (int j = 0; j < 4; ++j) {
        slo[j] = bf_lo(uu[j]);
        shi[j] = bf_hi(uu[j]);
        float v0 = slo[j] + dplo[j];
        float v1 = shi[j] + dphi[j];
        v0 = (v0 >= 0.f) ? v0 : 0.2f * v0;
        v1 = (v1 >= 0.f) ? v1 : 0.2f * v1;
        vp = fmaf(v0, avlo[j], vp);
        vp = fmaf(v1, avhi[j], vp);
      }
      vp += __shfl_xor(vp, 1, 64);  // head-local reduce (4-lane subgroup)
      vp += __shfl_xor(vp, 2, 64);
      float e = __expf(vp);
#pragma unroll
      for (int j = 0; j < 4; ++j) {
        acl[j] = fmaf(e, slo[j], acl[j]);
        ach[j] = fmaf(e, shi[j], ach[j]);
      }
      den += e;
      U0 = U1;
      U1 = U2;
      s2 = s3;
    }
  }
  // combine the 4 edge-groups (heads preserved: lanes with same m align)
#pragma unroll
  for (int off = 16; off < 64; off <<= 1) {
    den += __shfl_xor(den, off, 64);
#pragma unroll
    for (int j = 0; j < 4; ++j) {
      acl[j] += __shfl_xor(acl[j], off, 64);
      ach[j] += __shfl_xor(ach[j], off, 64);
    }
  }
  if (g == 0) {
    float a = pa[0];
    float r = 1.f / (den + 1e-16f);
#pragma unroll
    for (int j = 0; j < 4; ++j) {
      float o0 = acl[j] * r + x[(size_t)d * FF + cl[j]] + bias[cl[j]];
      float o1 = ach[j] * r + x[(size_t)d * FF + cl[j] + 16] + bias[cl[j] + 16];
      out[(size_t)d * FF + cl[j]] = (o0 >= 0.f) ? o0 : a * o0;
      out[(size_t)d * FF + cl[j] + 16] = (o1 >= 0.f) ? o1 : a * o1;
    }
  }
}

extern "C" void kernel_launch(void* const* d_in, const int* in_sizes, int n_in,
                              void* d_out, int out_size, void* d_ws, size_t ws_size,
                              hipStream_t stream) {
  const float* x = (const float*)d_in[0];
  const int* ei = (const int*)d_in[1];
  const float* bws = (const float*)d_in[2];
  const float* sws = (const float*)d_in[3];
  const float* bwd = (const float*)d_in[4];
  const float* swd = (const float*)d_in[5];
  const float* av = (const float*)d_in[6];
  const float* bias = (const float*)d_in[7];
  const float* pa = (const float*)d_in[8];

  // ws layout: Wh | projB | deg | ex | cur | row_ptr | partial | poff | scsr
  ushort* Wh = (ushort*)d_ws;
  uint* projB = (uint*)(Wh + (size_t)O2 * KT);
  int* deg = (int*)(projB + (size_t)NN * 128);
  int* ex = deg + NN;
  int* cur = ex + NN;
  int* row_ptr = cur + NN;         // NN+1 entries
  int* partial = row_ptr + NN + 1;
  int* poff = partial + 256;
  int* scsr = poff + 256;

  const int NB = (NN + 255) / 256;  // 196 scan blocks

  repack_zero_kernel<<<(O2 * KT + 255) / 256, 256, 0, stream>>>(bws, sws, bwd, swd, Wh, deg);
  proj_count_kernel<<<NPB + NCB, 256, 0, stream>>>(x, Wh, projB, ei, deg);
  scanA_kernel<<<NB, 256, 0, stream>>>(deg, ex, partial);
  scanB_kernel<<<1, 256, 0, stream>>>(partial, poff, NB);
  scanC_kernel<<<NB, 256, 0, stream>>>(ex, poff, row_ptr, cur);
  fill_kernel<<<(EE / 2 + 255) / 256, 256, 0, stream>>>(ei, cur, scsr);
  aggr_kernel<<<(NN + 3) / 4, 256, 0, stream>>>(projB, scsr, row_ptr, av, x, bias, pa,
                                                (float*)d_out);
}

// Round 3
// 262.331 us; speedup vs baseline: 1.3675x; 1.3675x over previous
//
#include <hip/hip_runtime.h>
#include <math.h>

// Problem constants (match reference)
#define NN 50000   // nodes
#define EE 800000  // edges
#define FF 128     // node features
#define CC 11      // spline coeffs per feature (G+K)
#define O2 256     // combined outputs: 128 src-proj + 128 dst-proj
#define KT 1536    // true K: 128 features x 12 slots (11 spline + silu)
#define NKC 8      // K-chunks of 192 (16 features x 12)
#define AROW 200   // A-tile row in shorts (192 + 8 pad)
#define NPB 782    // proj blocks: ceil(NN/64)
#define NCB 782    // count blocks: ceil(EE/(256*4))

typedef __attribute__((ext_vector_type(8))) short short8;
typedef __attribute__((ext_vector_type(4))) float f32x4;
typedef unsigned int uint;
typedef unsigned short ushort;

__device__ __forceinline__ ushort bf16_rne(float v) {
  uint u = __float_as_uint(v);
  u = u + 0x7FFFu + ((u >> 16) & 1u);
  return (ushort)(u >> 16);
}
__device__ __forceinline__ float bf_lo(uint u) { return __uint_as_float(u << 16); }
__device__ __forceinline__ float bf_hi(uint u) { return __uint_as_float(u & 0xffff0000u); }

// Repack weights to MFMA-fragment-contiguous bf16 layout:
// Wh[((g*16 + cg)*64 + lane)*8 + j] = W^T[col = cg*16+(lane&15)][k = g*32+(lane>>4)*8+j]
// so a wave's B-fragment load for (k-window g, col-group cg) is ONE coalesced
// 1KB read. Also zero deg (fused, removes memset dispatch).
__global__ __launch_bounds__(256) void repack_zero_kernel(
    const float* __restrict__ bws, const float* __restrict__ sws,
    const float* __restrict__ bwd, const float* __restrict__ swd,
    ushort* __restrict__ Wh, int* __restrict__ deg) {
  int idx = blockIdx.x * 256 + threadIdx.x;
  if (idx < NN) deg[idx] = 0;
  if (idx >= O2 * KT) return;
  int j = idx & 7;
  int lane = (idx >> 3) & 63;
  int cg = (idx >> 9) & 15;
  int g = idx >> 13;  // 0..47
  int col = cg * 16 + (lane & 15);
  int k = g * 32 + (lane >> 4) * 8 + j;
  int f = k / 12;
  int ch = k - f * 12;
  const float* bw = (col < 128) ? bws : bwd;
  const float* sw = (col < 128) ? sws : swd;
  int o = col & 127;
  float v = (ch == 11) ? bw[(size_t)o * FF + f] : sw[((size_t)o * FF + f) * CC + ch];
  Wh[idx] = bf16_rne(v);
}

// Fused dispatch: blocks [0,NPB) = MFMA projection; blocks [NPB,NPB+NCB) =
// degree count (4 edges/thread, int4). Count blocks backfill idle CU slots.
//
// Projection: block = 64 nodes x 256 cols, 4 waves (wave = 64x64 tile,
// acc[4][4]). K chunked by 192 (16 features), cooperative A-stage,
// double-buffered A-tile, one barrier per chunk.
// KEY CHANGE vs R0: B operand pipelined DEPTH-2 via parity register sets
// (bh[2][4], sk fully unrolled) -> loads issued at step g land at step g+2
// (~620+ cy in flight, covers L2 latency); no register copies, no per-step
// vmcnt drain. B reads are 1KB coalesced (fragment-contiguous Wh).
__global__ __launch_bounds__(256) void proj_count_kernel(
    const float* __restrict__ x, const ushort* __restrict__ Wh,
    uint* __restrict__ projB, const int* __restrict__ ei, int* __restrict__ deg) {
  __shared__ ushort Ah[2][64][AROW];  // 51.2 KB
  if (blockIdx.x >= NPB) {  // ---- count part ----
    int base = ((blockIdx.x - NPB) * 256 + threadIdx.x) * 4;
    if (base + 3 < EE) {
      int4 dd = *(const int4*)(ei + EE + base);
      atomicAdd(&deg[dd.x], 1);
      atomicAdd(&deg[dd.y], 1);
      atomicAdd(&deg[dd.z], 1);
      atomicAdd(&deg[dd.w], 1);
    } else {
      for (int j = 0; j < 4 && base + j < EE; ++j) atomicAdd(&deg[ei[EE + base + j]], 1);
    }
    return;
  }
  const int t = threadIdx.x;
  const int lane = t & 63;
  const int w = t >> 6;      // wave 0..3
  const int m = lane & 15;
  const int quad = lane >> 4;
  const int block0 = blockIdx.x * 64;
  const int gn = block0 + lane;  // staging: node = lane, feature quartet = wave
  const bool valid = (gn < NN);

  auto stage = [&](float4 xvv, ushort(*buf)[AROW]) {
    float xa[4] = {xvv.x, xvv.y, xvv.z, xvv.w};
    uint4* dz = (uint4*)&buf[lane][w * 48];
#pragma unroll
    for (int i = 0; i < 6; ++i) dz[i] = make_uint4(0u, 0u, 0u, 0u);
#pragma unroll
    for (int jf = 0; jf < 4; ++jf) {
      float xv = xa[jf];
      ushort* row = &buf[lane][w * 48 + jf * 12];
      row[11] = bf16_rne(xv / (1.f + __expf(-xv)));  // silu slot
      float u = fmaf(xv, 4.f, 7.f);
      float fj = floorf(u);
      int j = (int)fj;
      if (j >= 0 && j <= 13) {
        float tt = u - fj;
        float t2 = tt * tt, t3 = t2 * tt;
        float w0 = (1.f / 6.f) * (1.f - 3.f * tt + 3.f * t2 - t3);
        float w1 = (1.f / 6.f) * (4.f - 6.f * t2 + 3.f * t3);
        float w2 = (1.f / 6.f) * (1.f + 3.f * tt + 3.f * t2 - 3.f * t3);
        float w3 = (1.f / 6.f) * t3;
        float wv[4] = {w0, w1, w2, w3};
        int i0 = j - 3;
#pragma unroll
        for (int c = 0; c < 4; ++c) {
          int idx = i0 + c;
          if (idx >= 0 && idx <= 10) row[idx] = bf16_rne(wv[c]);
        }
      }
    }
  };

  f32x4 acc[4][4];
#pragma unroll
  for (int r = 0; r < 4; ++r)
#pragma unroll
    for (int c = 0; c < 4; ++c) acc[r][c] = (f32x4)(0.f);

  const float4 zero4 = make_float4(0.f, 0.f, 0.f, 0.f);
  float4 xv0 = valid ? *(const float4*)(x + (size_t)gn * FF + w * 4) : zero4;
  stage(xv0, Ah[0]);
  float4 xv_next = valid ? *(const float4*)(x + (size_t)gn * FF + 16 + w * 4) : zero4;

  // B pipeline prologue: global k-steps 0 and 1 into parity sets 0 and 1.
  // (Issued before the barrier; the barrier's vmcnt drain covers arrival.)
  short8 bh[2][4];
#pragma unroll
  for (int c = 0; c < 4; ++c) {
    bh[0][c] = *(const short8*)(Wh + (size_t)(0 * 16 + w * 4 + c) * 512 + (size_t)lane * 8);
    bh[1][c] = *(const short8*)(Wh + (size_t)(1 * 16 + w * 4 + c) * 512 + (size_t)lane * 8);
  }
  __syncthreads();

#pragma unroll 2
  for (int kc = 0; kc < NKC; ++kc) {
    float4 xv_pf = zero4;
    if (kc + 2 < NKC && valid)
      xv_pf = *(const float4*)(x + (size_t)gn * FF + (kc + 2) * 16 + w * 4);
    if (kc + 1 < NKC) stage(xv_next, Ah[(kc + 1) & 1]);
#pragma unroll
    for (int sk = 0; sk < 6; ++sk) {
      const int p = sk & 1;
      // A fragments, split 2+2 so the first MFMA group overlaps the second read
      short8 a0 = *(const short8*)(&Ah[kc & 1][0 * 16 + m][sk * 32 + quad * 8]);
      short8 a1 = *(const short8*)(&Ah[kc & 1][1 * 16 + m][sk * 32 + quad * 8]);
#pragma unroll
      for (int c = 0; c < 4; ++c)
        acc[0][c] = __builtin_amdgcn_mfma_f32_16x16x32_bf16(a0, bh[p][c], acc[0][c], 0, 0, 0);
#pragma unroll
      for (int c = 0; c < 4; ++c)
        acc[1][c] = __builtin_amdgcn_mfma_f32_16x16x32_bf16(a1, bh[p][c], acc[1][c], 0, 0, 0);
      short8 a2 = *(const short8*)(&Ah[kc & 1][2 * 16 + m][sk * 32 + quad * 8]);
      short8 a3 = *(const short8*)(&Ah[kc & 1][3 * 16 + m][sk * 32 + quad * 8]);
#pragma unroll
      for (int c = 0; c < 4; ++c)
        acc[2][c] = __builtin_amdgcn_mfma_f32_16x16x32_bf16(a2, bh[p][c], acc[2][c], 0, 0, 0);
#pragma unroll
      for (int c = 0; c < 4; ++c)
        acc[3][c] = __builtin_amdgcn_mfma_f32_16x16x32_bf16(a3, bh[p][c], acc[3][c], 0, 0, 0);
      // refill this parity set for global step g+2 (regs just freed; WAR-safe)
      int gnc = kc * 6 + sk + 2;
      if (gnc > 47) gnc = 47;  // harmless re-read on the last two steps
#pragma unroll
      for (int c = 0; c < 4; ++c)
        bh[p][c] = *(const short8*)(Wh + (size_t)(gnc * 16 + w * 4 + c) * 512 +
                                    (size_t)lane * 8);
    }
    __syncthreads();
    xv_next = xv_pf;
  }
  // epilogue: C/D layout col=lane&15, row=quad*4+reg (verified m89/m91).
  // pack c-pairs: p = q*16 + m, q = 2w + cp -> cols (q*32+m, q*32+16+m)
#pragma unroll
  for (int r = 0; r < 4; ++r) {
#pragma unroll
    for (int reg = 0; reg < 4; ++reg) {
      int nd = block0 + r * 16 + quad * 4 + reg;
      if (nd < NN) {
#pragma unroll
        for (int cp = 0; cp < 2; ++cp) {
          int q = 2 * w + cp;
          uint val = (uint)bf16_rne(acc[r][2 * cp][reg]) |
                     ((uint)bf16_rne(acc[r][2 * cp + 1][reg]) << 16);
          projB[(size_t)nd * 128 + q * 16 + m] = val;
        }
      }
    }
  }
}

// ---- CSR build ----
__global__ __launch_bounds__(256) void scanA_kernel(
    const int* __restrict__ deg, int* __restrict__ ex, int* __restrict__ partial) {
  __shared__ int sd[256];
  int t = threadIdx.x;
  int idx = blockIdx.x * 256 + t;
  int v = (idx < NN) ? deg[idx] : 0;
  sd[t] = v;
  __syncthreads();
#pragma unroll
  for (int off = 1; off < 256; off <<= 1) {
    int add = (t >= off) ? sd[t - off] : 0;
    __syncthreads();
    sd[t] += add;
    __syncthreads();
  }
  if (idx < NN) ex[idx] = sd[t] - v;
  if (t == 255) partial[blockIdx.x] = sd[255];
}

__global__ __launch_bounds__(256) void scanB_kernel(
    const int* __restrict__ partial, int* __restrict__ poff, int nblk) {
  __shared__ int sd[256];
  int t = threadIdx.x;
  int v = (t < nblk) ? partial[t] : 0;
  sd[t] = v;
  __syncthreads();
#pragma unroll
  for (int off = 1; off < 256; off <<= 1) {
    int add = (t >= off) ? sd[t - off] : 0;
    __syncthreads();
    sd[t] += add;
    __syncthreads();
  }
  if (t < nblk) poff[t] = sd[t] - v;
}

__global__ __launch_bounds__(256) void scanC_kernel(
    const int* __restrict__ ex, const int* __restrict__ poff,
    int* __restrict__ row_ptr, int* __restrict__ cur) {
  int idx = blockIdx.x * 256 + threadIdx.x;
  if (idx < NN) {
    int v = ex[idx] + poff[idx >> 8];
    row_ptr[idx] = v;
    cur[idx] = v;
  }
  if (idx == 0) row_ptr[NN] = EE;
}

// 2 edges/thread, int2 loads; store SRC id directly
__global__ __launch_bounds__(256) void fill_kernel(
    const int* __restrict__ ei, int* __restrict__ cur, int* __restrict__ scsr) {
  int base = (blockIdx.x * 256 + threadIdx.x) * 2;
  if (base + 1 < EE) {
    int2 ss = *(const int2*)(ei + base);
    int2 dd = *(const int2*)(ei + EE + base);
    int p0 = atomicAdd(&cur[dd.x], 1);
    scsr[p0] = ss.x;
    int p1 = atomicAdd(&cur[dd.y], 1);
    scsr[p1] = ss.y;
  } else if (base < EE) {
    int s = ei[base], d = ei[EE + base];
    scsr[atomicAdd(&cur[d], 1)] = s;
  }
}

// Per-dst aggregation: one wave per dst, 4 edges in flight (16-lane groups),
// 2-deep gather pipeline (src idx 3 ahead, row data 2 ahead).
__global__ __launch_bounds__(256) void aggr_kernel(
    const uint* __restrict__ projB, const int* __restrict__ scsr,
    const int* __restrict__ row_ptr, const float* __restrict__ av,
    const float* __restrict__ x, const float* __restrict__ bias,
    const float* __restrict__ pa, float* __restrict__ out) {
  int d = blockIdx.x * 4 + (threadIdx.x >> 6);
  if (d >= NN) return;
  int l = threadIdx.x & 63;
  int g = l >> 4, m = l & 15;
  const uint4* pb4 = (const uint4*)projB;
  uint4 dpu = pb4[(size_t)d * 32 + 16 + m];
  uint du[4] = {dpu.x, dpu.y, dpu.z, dpu.w};
  float dplo[4], dphi[4], avlo[4], avhi[4];
  int cl[4];
#pragma unroll
  for (int j = 0; j < 4; ++j) {
    dplo[j] = bf_lo(du[j]);
    dphi[j] = bf_hi(du[j]);
    int p = 4 * m + j;
    cl[j] = ((p >> 4) << 5) + (p & 15);
    avlo[j] = av[cl[j]];
    avhi[j] = av[cl[j] + 16];
  }
  int i0 = row_ptr[d], i1 = row_ptr[d + 1];
  float acl[4] = {0.f, 0.f, 0.f, 0.f}, ach[4] = {0.f, 0.f, 0.f, 0.f};
  float den = 0.f;
  int i = i0 + g;
  if (i < i1) {
    int s0 = scsr[i];
    int s1 = (i + 4 < i1) ? scsr[i + 4] : s0;
    int s2 = (i + 8 < i1) ? scsr[i + 8] : s1;
    uint4 U0 = pb4[(size_t)s0 * 32 + m];
    uint4 U1 = pb4[(size_t)s1 * 32 + m];
    for (; i < i1; i += 4) {
      int s3 = (i + 12 < i1) ? scsr[i + 12] : s2;
      uint4 U2 = pb4[(size_t)s2 * 32 + m];  // 2-ahead, issues immediately
      uint uu[4] = {U0.x, U0.y, U0.z, U0.w};
      float slo[4], shi[4];
      float vp = 0.f;
#pragma unroll
      for (int j = 0; j < 4; ++j) {
        slo[j] = bf_lo(uu[j]);
        shi[j] = bf_hi(uu[j]);
        float v0 = slo[j] + dplo[j];
        float v1 = shi[j] + dphi[j];
        v0 = (v0 >= 0.f) ? v0 : 0.2f * v0;
        v1 = (v1 >= 0.f) ? v1 : 0.2f * v1;
        vp = fmaf(v0, avlo[j], vp);
        vp = fmaf(v1, avhi[j], vp);
      }
      vp += __shfl_xor(vp, 1, 64);  // head-local reduce (4-lane subgroup)
      vp += __shfl_xor(vp, 2, 64);
      float e = __expf(vp);
#pragma unroll
      for (int j = 0; j < 4; ++j) {
        acl[j] = fmaf(e, slo[j], acl[j]);
        ach[j] = fmaf(e, shi[j], ach[j]);
      }
      den += e;
      U0 = U1;
      U1 = U2;
      s2 = s3;
    }
  }
  // combine the 4 edge-groups (heads preserved: lanes with same m align)
#pragma unroll
  for (int off = 16; off < 64; off <<= 1) {
    den += __shfl_xor(den, off, 64);
#pragma unroll
    for (int j = 0; j < 4; ++j) {
      acl[j] += __shfl_xor(acl[j], off, 64);
      ach[j] += __shfl_xor(ach[j], off, 64);
    }
  }
  if (g == 0) {
    float a = pa[0];
    float r = 1.f / (den + 1e-16f);
#pragma unroll
    for (int j = 0; j < 4; ++j) {
      float o0 = acl[j] * r + x[(size_t)d * FF + cl[j]] + bias[cl[j]];
      float o1 = ach[j] * r + x[(size_t)d * FF + cl[j] + 16] + bias[cl[j] + 16];
      out[(size_t)d * FF + cl[j]] = (o0 >= 0.f) ? o0 : a * o0;
      out[(size_t)d * FF + cl[j] + 16] = (o1 >= 0.f) ? o1 : a * o1;
    }
  }
}

extern "C" void kernel_launch(void* const* d_in, const int* in_sizes, int n_in,
                              void* d_out, int out_size, void* d_ws, size_t ws_size,
                              hipStream_t stream) {
  const float* x = (const float*)d_in[0];
  const int* ei = (const int*)d_in[1];
  const float* bws = (const float*)d_in[2];
  const float* sws = (const float*)d_in[3];
  const float* bwd = (const float*)d_in[4];
  const float* swd = (const float*)d_in[5];
  const float* av = (const float*)d_in[6];
  const float* bias = (const float*)d_in[7];
  const float* pa = (const float*)d_in[8];

  // ws layout: Wh | projB | deg | ex | cur | row_ptr | partial | poff | scsr
  ushort* Wh = (ushort*)d_ws;
  uint* projB = (uint*)(Wh + (size_t)O2 * KT);
  int* deg = (int*)(projB + (size_t)NN * 128);
  int* ex = deg + NN;
  int* cur = ex + NN;
  int* row_ptr = cur + NN;         // NN+1 entries
  int* partial = row_ptr + NN + 1;
  int* poff = partial + 256;
  int* scsr = poff + 256;

  const int NB = (NN + 255) / 256;  // 196 scan blocks

  repack_zero_kernel<<<(O2 * KT + 255) / 256, 256, 0, stream>>>(bws, sws, bwd, swd, Wh, deg);
  proj_count_kernel<<<NPB + NCB, 256, 0, stream>>>(x, Wh, projB, ei, deg);
  scanA_kernel<<<NB, 256, 0, stream>>>(deg, ex, partial);
  scanB_kernel<<<1, 256, 0, stream>>>(partial, poff, NB);
  scanC_kernel<<<NB, 256, 0, stream>>>(ex, poff, row_ptr, cur);
  fill_kernel<<<(EE / 2 + 255) / 256, 256, 0, stream>>>(ei, cur, scsr);
  aggr_kernel<<<(NN + 3) / 4, 256, 0, stream>>>(projB, scsr, row_ptr, av, x, bias, pa,
                                                (float*)d_out);
}